// Round 5
// baseline (2977.199 us; speedup 1.0000x reference)
//
#include <hip/hip_runtime.h>

// LSTM B=64, S=512, D=H=512 — persistent kernel, latency-hiding schedule.
// Round-4 post-mortem: sync mechanism was fine; the SCHEDULE serialized
// x HBM loads (~2000cy), h LLC loads (~800cy), and store drains into the
// per-step critical path -> 5.5us/step. This round hides them:
//  - x(t+1) loads issued AFTER the h-store-drain barrier; the next
//    vmcnt-draining barrier is post-poll, so poll slack absorbs HBM latency.
//  - h loads issued right after the poll barrier, consumed after
//    x-repack + x-GEMM (~400cy hiding).
//  - h uints bit-cast straight to bf16x8 fragments (no unpack VALU).
// Topology: 128 WGs = 4 groups (16 batch rows) x 32 slices (64 gate cols).
// LDS: A 16KB | gates 4KB | B=[W;U] 128KB (swizzled, coalesced init).

#define NG   4
#define GR   16
#define NS   32
#define SC   16
#define DIM  512
#define HID  512
#define SEQ  512
#define NTHR 256
#define NWG  (NG*NS)

#define AOFF 0
#define GOFF (GR*1024)                  // gates: 16x64 f32 = 4 KB
#define BOFF (GOFF + 4096)
#define LDS_BYTES (BOFF + 64*2048)      // 16K + 4K + 128K = 151552

#define WS_FLAG_BYTES 16384             // 4 groups x 32 flags x 128 B
#define HBUF_UINTS   (2*NG*GR*256)      // 2 parities x 64 rows x 256 uints
#define WS_NEED      (WS_FLAG_BYTES + HBUF_UINTS*4)

typedef float f32x4  __attribute__((ext_vector_type(4)));
typedef short bf16x8 __attribute__((ext_vector_type(8)));

union HPack { unsigned u[4]; bf16x8 v; };

__device__ __forceinline__ unsigned short f2bf(float f){
  union { float f; unsigned u; } v; v.f = f;
  unsigned r = v.u + 0x7fffu + ((v.u >> 16) & 1u);   // RNE
  return (unsigned short)(r >> 16);
}
__device__ __forceinline__ float sigm(float x){ return 1.0f/(1.0f + __expf(-x)); }
__device__ __forceinline__ float tanh_f(float x){
  float e = __expf(-2.0f * fabsf(x));
  float t = (1.0f - e)/(1.0f + e);
  return x < 0.0f ? -t : t;
}

__global__ void zero_ws_kernel(uint4* p, int n4){
  int i = blockIdx.x*blockDim.x + threadIdx.x;
  uint4 z; z.x=0u; z.y=0u; z.z=0u; z.w=0u;
  if (i < n4) p[i] = z;
}

__global__ __launch_bounds__(NTHR, 1) void lstm_persistent(
  const float* __restrict__ x,
  const float* __restrict__ W0, const float* __restrict__ W1,
  const float* __restrict__ W2, const float* __restrict__ W3,
  const float* __restrict__ U0, const float* __restrict__ U1,
  const float* __restrict__ U2, const float* __restrict__ U3,
  const float* __restrict__ b0, const float* __restrict__ b1,
  const float* __restrict__ b2, const float* __restrict__ b3,
  float* __restrict__ out,
  unsigned* __restrict__ flags,
  unsigned* __restrict__ hbuf32)
{
  __shared__ __align__(16) char smem[LDS_BYTES];
  const int tid = threadIdx.x;
  const int bid = blockIdx.x;
  const int g = bid >> 5;       // batch group 0..3 (contiguous -> XCD spread)
  const int s = bid & 31;       // h-slice (gate cols 64s'… : 16 h-cols)
  const int w = tid >> 6;       // wave = gate (i,f,o,c)
  const int l = tid & 63;

  // ---- one-time: stage B = [W;U] slice into LDS, coalesced reads ----
  {
    const int q  = tid & 3;
    const int kk = tid >> 2;
    for (int gate = 0; gate < 4; ++gate){
      const float* Wsrc = (gate==0)?W0:(gate==1)?W1:(gate==2)?W2:W3;
      const float* Usrc = (gate==0)?U0:(gate==1)?U1:(gate==2)?U2:U3;
      #pragma unroll
      for (int kb = 0; kb < 16; ++kb){
        const int k = kb*64 + kk;
        const float* p = (k < DIM)
          ? (Wsrc + (size_t)k*HID + s*SC + q*4)
          : (Usrc + (size_t)(k-DIM)*HID + s*SC + q*4);
        f32x4 v = *(const f32x4*)p;
        #pragma unroll
        for (int j = 0; j < 4; ++j){
          const int c = gate*16 + q*4 + j;
          const unsigned byte = ((unsigned)(k*2)) ^ ((unsigned)((c&7)<<4));
          *(unsigned short*)(&smem[BOFF + c*2048] + byte) = f2bf(v[j]);
        }
      }
    }
  }

  // elementwise mapping
  const int er = tid >> 4;
  const int ec = tid & 15;
  const int ecol = s*SC + ec;
  const float bi = b0[ecol], bff = b1[ecol], bo = b2[ecol], bc = b3[ecol];
  float cstate = 0.0f, hout = 0.0f;

  // MFMA fragment constants
  const int arow = l & 15;
  const int qh   = l >> 4;
  const unsigned swz = (unsigned)((arow & 7) << 4);
  const char* Abase = &smem[AOFF + arow*1024];
  const char* Bbase = &smem[BOFF + (w*16 + arow)*2048];
  float* gatesLds = (float*)&smem[GOFF];

  // staging mapping: thread -> (row sr 0..15, 32-elem chunk sdb 0..15)
  const int sr  = tid >> 4;
  const int sdb = tid & 15;
  const unsigned swzS = (unsigned)((sr & 7) << 4);
  char* Arow = &smem[AOFF + sr*1024];

  unsigned* gflags = flags + g*1024;    // 32 flags, 128 B apart
  const float* xrow = x + (size_t)(g*GR + sr)*SEQ*DIM + sdb*32;
  const unsigned* hrow_base = hbuf32 + (size_t)(g*GR + sr)*256 + sdb*16;

  f32x4 xr[8];        // x(t) prefetch: 32 floats/thread
  HPack hp[4];        // h(t-1): 16 uints/thread

#define GEMM_STEP(QA, QB, ACC) do { \
    bf16x8 a_ = *(const bf16x8*)(Abase + (((unsigned)((QA)*64 + qh*16)) ^ swz)); \
    bf16x8 b_ = *(const bf16x8*)(Bbase + (((unsigned)((QB)*64 + qh*16)) ^ swz)); \
    ACC = __builtin_amdgcn_mfma_f32_16x16x32_bf16(a_, b_, ACC, 0, 0, 0); \
  } while(0)

  // prologue: issue x(0) loads (drained at first bar1)
  {
    const float* xp = xrow;             // t=0
    #pragma unroll
    for (int j = 0; j < 8; ++j) xr[j] = *(const f32x4*)(xp + j*4);
  }

  __syncthreads();                      // weights staged

  for (int t = 0; t < SEQ; ++t){
    // 1) poll: h(t-1) producers (slack here also covers xr load latency)
    if (t > 0 && tid < 32){
      const unsigned* fp = &gflags[tid*32];
      while (__hip_atomic_load(fp, __ATOMIC_RELAXED, __HIP_MEMORY_SCOPE_AGENT)
             < (unsigned)t) { }
    }
    __syncthreads();                                   // bar1

    // 2) issue h(t-1) loads early (latency hidden behind x repack + x-GEMM)
    if (t > 0){
      const unsigned* hsrc = hrow_base + (size_t)((t&1)*NG)*GR*256;
      #pragma unroll
      for (int j = 0; j < 4; ++j){
        #pragma unroll
        for (int e = 0; e < 4; ++e)
          hp[j].u[e] = __hip_atomic_load(hsrc + j*4 + e, __ATOMIC_RELAXED,
                                         __HIP_MEMORY_SCOPE_AGENT);
      }
    }

    // 3) repack x(t): xr regs -> A (fp32->bf16, swizzled)
    #pragma unroll
    for (int j = 0; j < 4; ++j){
      f32x4 u = xr[2*j], v = xr[2*j+1];
      bf16x8 o8;
      o8[0]=(short)f2bf(u[0]); o8[1]=(short)f2bf(u[1]);
      o8[2]=(short)f2bf(u[2]); o8[3]=(short)f2bf(u[3]);
      o8[4]=(short)f2bf(v[0]); o8[5]=(short)f2bf(v[1]);
      o8[6]=(short)f2bf(v[2]); o8[7]=(short)f2bf(v[3]);
      *(bf16x8*)(Arow + (((unsigned)(sdb*64 + j*16)) ^ swzS)) = o8;
    }
    __syncthreads();                                   // bar2: x staged

    f32x4 acc0 = {0.f,0.f,0.f,0.f}, acc1 = {0.f,0.f,0.f,0.f};
    f32x4 acc2 = {0.f,0.f,0.f,0.f}, acc3 = {0.f,0.f,0.f,0.f};

    // 4) x-half GEMM (B rows 0..511 = W)
    #pragma unroll
    for (int q4 = 0; q4 < 4; ++q4){
      GEMM_STEP(q4*4+0, q4*4+0, acc0);
      GEMM_STEP(q4*4+1, q4*4+1, acc1);
      GEMM_STEP(q4*4+2, q4*4+2, acc2);
      GEMM_STEP(q4*4+3, q4*4+3, acc3);
    }
    __syncthreads();                                   // bar3: A free

    // 5) repack h(t-1): hp regs -> A (bit-cast, no unpack VALU)
    if (t > 0){
      #pragma unroll
      for (int j = 0; j < 4; ++j)
        *(bf16x8*)(Arow + (((unsigned)(sdb*64 + j*16)) ^ swzS)) = hp[j].v;
    }
    __syncthreads();                                   // bar4: h staged

    // 6) h-half GEMM (B rows 512..1023 = U)
    if (t > 0){
      #pragma unroll
      for (int q4 = 0; q4 < 4; ++q4){
        GEMM_STEP(q4*4+0, q4*4+16, acc0);
        GEMM_STEP(q4*4+1, q4*4+17, acc1);
        GEMM_STEP(q4*4+2, q4*4+18, acc2);
        GEMM_STEP(q4*4+3, q4*4+19, acc3);
      }
    }

    // 7) gate exchange (dedicated region; C/D: col=l&15, row=4*qh+rr)
    f32x4 accs = (acc0 + acc1) + (acc2 + acc3);
    #pragma unroll
    for (int rr = 0; rr < 4; ++rr)
      gatesLds[(qh*4 + rr)*64 + w*16 + arow] = accs[rr];
    __syncthreads();                                   // bar5: gates ready

    // 8) elementwise cell; packed h store (relaxed agent atomics)
    {
      float gi = gatesLds[er*64 +  0 + ec] + bi;
      float gf = gatesLds[er*64 + 16 + ec] + bff;
      float go = gatesLds[er*64 + 32 + ec] + bo;
      float gc = gatesLds[er*64 + 48 + ec] + bc;
      float ig = sigm(gi), fg = sigm(gf), og = sigm(go), ct = tanh_f(gc);
      cstate = fg*cstate + ig*ct;
      hout = og * tanh_f(cstate);
      unsigned hb = (unsigned)f2bf(hout);
      unsigned ob = __shfl_xor(hb, 1);
      if ((tid & 1) == 0){
        unsigned val = hb | (ob << 16);
        unsigned idx = (unsigned)((((t+1)&1)*NG + g)*GR + er)*256u
                     + (unsigned)(s*8 + (ec>>1));
        __hip_atomic_store(hbuf32 + idx, val, __ATOMIC_RELAXED,
                           __HIP_MEMORY_SCOPE_AGENT);
      }
    }
    __syncthreads();            // bar6: h stores vmcnt-drained (ack'd at LLC)

    // 9) issue x(t+1) loads AFTER the drain barrier -> next vmcnt-draining
    //    barrier is post-poll bar1, so poll slack absorbs the HBM latency.
    {
      const int tn = (t + 1 < SEQ) ? (t + 1) : t;
      const float* xp = xrow + (size_t)tn*DIM;
      #pragma unroll
      for (int j = 0; j < 8; ++j) xr[j] = *(const f32x4*)(xp + j*4);
    }

    // 10) release flag (h already drained at bar6)
    if (tid == 0)
      __hip_atomic_store(&gflags[s*32], (unsigned)(t+1),
                         __ATOMIC_RELAXED, __HIP_MEMORY_SCOPE_AGENT);
  }

  out[(size_t)(g*GR + er)*HID + s*SC + ec] = hout;
#undef GEMM_STEP
}

extern "C" void kernel_launch(void* const* d_in, const int* in_sizes, int n_in,
                              void* d_out, int out_size, void* d_ws, size_t ws_size,
                              hipStream_t stream)
{
  (void)in_sizes; (void)n_in; (void)out_size;
  if (ws_size < (size_t)WS_NEED) return;

  const float* x  = (const float*)d_in[0];
  const float* W0 = (const float*)d_in[1];
  const float* W1 = (const float*)d_in[2];
  const float* W2 = (const float*)d_in[3];
  const float* W3 = (const float*)d_in[4];
  const float* U0 = (const float*)d_in[5];
  const float* U1 = (const float*)d_in[6];
  const float* U2 = (const float*)d_in[7];
  const float* U3 = (const float*)d_in[8];
  const float* b0 = (const float*)d_in[9];
  const float* b1 = (const float*)d_in[10];
  const float* b2 = (const float*)d_in[11];
  const float* b3 = (const float*)d_in[12];
  float* out = (float*)d_out;

  unsigned* flags  = (unsigned*)d_ws;
  unsigned* hbuf32 = (unsigned*)((char*)d_ws + WS_FLAG_BYTES);

  const int n4 = WS_NEED / 16;
  zero_ws_kernel<<<dim3((n4 + 255)/256), dim3(256), 0, stream>>>((uint4*)d_ws, n4);
  lstm_persistent<<<dim3(NWG), dim3(NTHR), 0, stream>>>(
      x, W0,W1,W2,W3, U0,U1,U2,U3, b0,b1,b2,b3, out, flags, hbuf32);
}

// Round 7
// 2589.115 us; speedup vs baseline: 1.1499x; 1.1499x over previous
//
#include <hip/hip_runtime.h>

// LSTM B=64, S=512, D=H=512 — persistent kernel, TAG-IN-DATA protocol.
// Rounds 1-5 all ~5.5us/step regardless of sync mechanism/schedule => the
// protocol SHAPE was the bottleneck: 4 serialized fabric round trips per step
// (h-store drain, flag store, flag poll, h load) + every __syncthreads()
// draining vmcnt(0) (store acks + prefetches forced onto the critical path).
// This round:
//  (1) h words carry their own tag: ulong = (tag<<32)|2xbf16, relaxed
//      agent-scope atomics. Consumers poll the data words directly.
//      Data+flag = one message => 2 fabric hops/step instead of 4.
//      No producer drain at all (word atomicity replaces ordering).
//      Overwrite-safety: storing tag t+3 over t+1 requires having observed
//      ALL tags t+2, which publishers emit only after their t+1 reads
//      retired; parity double-buffer => no deadlock.
//  (2) barriers are lgkmcnt-only (inline asm s_waitcnt lgkmcnt(0);s_barrier):
//      LDS ordering preserved, but global stores/loads stay in flight
//      across barriers (vmcnt never forced to 0 in the loop).
// Topology: 128 WGs = 4 groups (16 batch rows) x 32 slices (64 gate cols),
// B=[W;U] 1024x64 bf16 resident in LDS (128KB swizzled, coalesced init).

#define NG   4
#define GR   16
#define NS   32
#define SC   16
#define DIM  512
#define HID  512
#define SEQ  512
#define NTHR 256
#define NWG  (NG*NS)

#define AOFF 0
#define GOFF (GR*1024)                  // gates: 16x64 f32 = 4 KB
#define BOFF (GOFF + 4096)
#define LDS_BYTES (BOFF + 64*2048)      // 16K + 4K + 128K = 151552

#define HBUF_WORDS (2*NG*GR*256)        // 2 parities x 64 rows x 256 ulong
#define WS_NEED    (HBUF_WORDS*8)       // 256 KB

typedef float f32x4  __attribute__((ext_vector_type(4)));
typedef short bf16x8 __attribute__((ext_vector_type(8)));
typedef unsigned long long u64;

union Pk { unsigned u[4]; bf16x8 v; };

// lgkmcnt-only barrier: orders LDS producer->consumer, does NOT drain vmcnt
// (global store acks / prefetch loads stay in flight across it).
#define BARRIER() asm volatile("s_waitcnt lgkmcnt(0)\n\ts_barrier" ::: "memory")

__device__ __forceinline__ unsigned short f2bf(float f){
  union { float f; unsigned u; } v; v.f = f;
  unsigned r = v.u + 0x7fffu + ((v.u >> 16) & 1u);   // RNE
  return (unsigned short)(r >> 16);
}
__device__ __forceinline__ float sigm(float x){ return 1.0f/(1.0f + __expf(-x)); }
__device__ __forceinline__ float tanh_f(float x){
  float e = __expf(-2.0f * fabsf(x));
  float t = (1.0f - e)/(1.0f + e);
  return x < 0.0f ? -t : t;
}

__global__ void zero_ws_kernel(uint4* p, int n4){
  int i = blockIdx.x*blockDim.x + threadIdx.x;
  uint4 z; z.x=0u; z.y=0u; z.z=0u; z.w=0u;
  if (i < n4) p[i] = z;
}

__global__ __launch_bounds__(NTHR, 1) void lstm_persistent(
  const float* __restrict__ x,
  const float* __restrict__ W0, const float* __restrict__ W1,
  const float* __restrict__ W2, const float* __restrict__ W3,
  const float* __restrict__ U0, const float* __restrict__ U1,
  const float* __restrict__ U2, const float* __restrict__ U3,
  const float* __restrict__ b0, const float* __restrict__ b1,
  const float* __restrict__ b2, const float* __restrict__ b3,
  float* __restrict__ out,
  u64* __restrict__ hbuf)
{
  __shared__ __align__(16) char smem[LDS_BYTES];
  const int tid = threadIdx.x;
  const int bid = blockIdx.x;
  const int g = bid >> 5;       // batch group 0..3 (contiguous -> XCD spread)
  const int s = bid & 31;       // h-slice (16 h-cols -> 64 gate cols)
  const int w = tid >> 6;       // wave = gate (i,f,o,c)
  const int l = tid & 63;

  // ---- one-time: stage B = [W;U] slice into LDS, coalesced reads ----
  {
    const int q  = tid & 3;
    const int kk = tid >> 2;
    for (int gate = 0; gate < 4; ++gate){
      const float* Wsrc = (gate==0)?W0:(gate==1)?W1:(gate==2)?W2:W3;
      const float* Usrc = (gate==0)?U0:(gate==1)?U1:(gate==2)?U2:U3;
      #pragma unroll
      for (int kb = 0; kb < 16; ++kb){
        const int k = kb*64 + kk;
        const float* p = (k < DIM)
          ? (Wsrc + (size_t)k*HID + s*SC + q*4)
          : (Usrc + (size_t)(k-DIM)*HID + s*SC + q*4);
        f32x4 v = *(const f32x4*)p;
        #pragma unroll
        for (int j = 0; j < 4; ++j){
          const int c = gate*16 + q*4 + j;
          const unsigned byte = ((unsigned)(k*2)) ^ ((unsigned)((c&7)<<4));
          *(unsigned short*)(&smem[BOFF + c*2048] + byte) = f2bf(v[j]);
        }
      }
    }
  }

  // elementwise mapping
  const int er = tid >> 4;
  const int ec = tid & 15;
  const int ecol = s*SC + ec;
  const float bi = b0[ecol], bff = b1[ecol], bo = b2[ecol], bc = b3[ecol];
  float cstate = 0.0f, hout = 0.0f;

  // MFMA fragment constants
  const int arow = l & 15;
  const int qh   = l >> 4;
  const unsigned swz = (unsigned)((arow & 7) << 4);
  const char* Abase = &smem[AOFF + arow*1024];
  const char* Bbase = &smem[BOFF + (w*16 + arow)*2048];
  float* gatesLds = (float*)&smem[GOFF];

  // staging mapping: thread -> (row sr 0..15, 32-elem chunk sdb 0..15)
  const int sr  = tid >> 4;
  const int sdb = tid & 15;
  const unsigned swzS = (unsigned)((sr & 7) << 4);
  char* Arow = &smem[AOFF + sr*1024];

  const float* xrow = x + (size_t)(g*GR + sr)*SEQ*DIM + sdb*32;
  // consumer view: 16 ulong words = rows sr, col-pairs sdb*16..+15
  const u64* hsrc0 = hbuf + ((size_t)g*GR + sr)*256 + sdb*16;           // parity 0
  const u64* hsrc1 = hbuf + ((size_t)(NG + g)*GR + sr)*256 + sdb*16;    // parity 1
  // producer word index (even threads): row er, pair s*8 + ec/2
  const size_t pidx = ((size_t)g*GR + er)*256 + (size_t)(s*8 + (ec>>1));

  f32x4 xr[8];        // x(t) prefetch: 32 floats/thread
  u64   hp[16];       // h(t-1) tagged words

#define GEMM_STEP(QA, QB, ACC) do { \
    bf16x8 a_ = *(const bf16x8*)(Abase + (((unsigned)((QA)*64 + qh*16)) ^ swz)); \
    bf16x8 b_ = *(const bf16x8*)(Bbase + (((unsigned)((QB)*64 + qh*16)) ^ swz)); \
    ACC = __builtin_amdgcn_mfma_f32_16x16x32_bf16(a_, b_, ACC, 0, 0, 0); \
  } while(0)

  // prologue: issue x(0) loads
  #pragma unroll
  for (int j = 0; j < 8; ++j) xr[j] = *(const f32x4*)(xrow + j*4);

  __syncthreads();                      // weights staged (one-time, full sync)

  for (int t = 0; t < SEQ; ++t){
    // 1) repack x(t): regs -> A (fp32->bf16, swizzled)
    #pragma unroll
    for (int j = 0; j < 4; ++j){
      f32x4 u = xr[2*j], v = xr[2*j+1];
      bf16x8 o8;
      o8[0]=(short)f2bf(u[0]); o8[1]=(short)f2bf(u[1]);
      o8[2]=(short)f2bf(u[2]); o8[3]=(short)f2bf(u[3]);
      o8[4]=(short)f2bf(v[0]); o8[5]=(short)f2bf(v[1]);
      o8[6]=(short)f2bf(v[2]); o8[7]=(short)f2bf(v[3]);
      *(bf16x8*)(Arow + (((unsigned)(sdb*64 + j*16)) ^ swzS)) = o8;
    }
    BARRIER();                                         // bar1: x staged

    // 2) issue first-pass h(t-1) tagged loads (latency hides under x-GEMM)
    const u64* hsrc = (t & 1) ? hsrc1 : hsrc0;
    if (t > 0){
      #pragma unroll
      for (int j = 0; j < 16; ++j)
        hp[j] = __hip_atomic_load(hsrc + j, __ATOMIC_RELAXED,
                                  __HIP_MEMORY_SCOPE_AGENT);
    }

    f32x4 acc0 = {0.f,0.f,0.f,0.f}, acc1 = {0.f,0.f,0.f,0.f};
    f32x4 acc2 = {0.f,0.f,0.f,0.f}, acc3 = {0.f,0.f,0.f,0.f};

    // 3) x-half GEMM (B rows 0..511 = W)
    #pragma unroll
    for (int q4 = 0; q4 < 4; ++q4){
      GEMM_STEP(q4*4+0, q4*4+0, acc0);
      GEMM_STEP(q4*4+1, q4*4+1, acc1);
      GEMM_STEP(q4*4+2, q4*4+2, acc2);
      GEMM_STEP(q4*4+3, q4*4+3, acc3);
    }
    BARRIER();                                         // bar2: A free

    // 4) poll-fix stale words, then repack h -> A (low 32b = 2xbf16)
    if (t > 0){
      const unsigned want = (unsigned)t;
      unsigned pend = 0xffffu;
      while (pend){
        unsigned np = 0u;
        #pragma unroll
        for (int j = 0; j < 16; ++j){
          if (pend & (1u << j)){
            if ((unsigned)(hp[j] >> 32) != want){
              hp[j] = __hip_atomic_load(hsrc + j, __ATOMIC_RELAXED,
                                        __HIP_MEMORY_SCOPE_AGENT);
              if ((unsigned)(hp[j] >> 32) != want) np |= (1u << j);
            }
          }
        }
        pend = np;
      }
      #pragma unroll
      for (int q = 0; q < 4; ++q){
        Pk pk;
        #pragma unroll
        for (int e = 0; e < 4; ++e) pk.u[e] = (unsigned)hp[q*4 + e];
        *(bf16x8*)(Arow + (((unsigned)(sdb*64 + q*16)) ^ swzS)) = pk.v;
      }
    }
    BARRIER();                                         // bar3: h staged

    // 5) h-half GEMM (B rows 512..1023 = U)
    if (t > 0){
      #pragma unroll
      for (int q4 = 0; q4 < 4; ++q4){
        GEMM_STEP(q4*4+0, q4*4+16, acc0);
        GEMM_STEP(q4*4+1, q4*4+17, acc1);
        GEMM_STEP(q4*4+2, q4*4+18, acc2);
        GEMM_STEP(q4*4+3, q4*4+19, acc3);
      }
    }

    // 6) prefetch x(t+1) -> regs; stays in flight across lgkm-only barriers
    {
      const int tn = (t + 1 < SEQ) ? (t + 1) : t;
      const float* xp = xrow + (size_t)tn*DIM;
      #pragma unroll
      for (int j = 0; j < 8; ++j) xr[j] = *(const f32x4*)(xp + j*4);
    }

    // 7) gate exchange (C/D: col=l&15, row=4*qh+rr)
    f32x4 accs = (acc0 + acc1) + (acc2 + acc3);
    #pragma unroll
    for (int rr = 0; rr < 4; ++rr)
      gatesLds[(qh*4 + rr)*64 + w*16 + arow] = accs[rr];
    BARRIER();                                         // bar4: gates ready

    // 8) elementwise cell; tagged h store (fire-and-forget, no drain)
    {
      float gi = gatesLds[er*64 +  0 + ec] + bi;
      float gf = gatesLds[er*64 + 16 + ec] + bff;
      float go = gatesLds[er*64 + 32 + ec] + bo;
      float gc = gatesLds[er*64 + 48 + ec] + bc;
      float ig = sigm(gi), fg = sigm(gf), og = sigm(go), ct = tanh_f(gc);
      cstate = fg*cstate + ig*ct;
      hout = og * tanh_f(cstate);
      unsigned hb = (unsigned)f2bf(hout);
      unsigned ob = __shfl_xor(hb, 1);
      if ((tid & 1) == 0){
        u64 val = ((u64)(unsigned)(t + 1) << 32)
                | (u64)(hb | (ob << 16));
        u64* dst = hbuf + (size_t)(((t+1)&1)*NG)*GR*256 + pidx;
        __hip_atomic_store(dst, val, __ATOMIC_RELAXED,
                           __HIP_MEMORY_SCOPE_AGENT);
      }
    }
    // no barrier here: gatesLds not rewritten until after next bar1+bar2
  }

  out[(size_t)(g*GR + er)*HID + s*SC + ec] = hout;
#undef GEMM_STEP
}

extern "C" void kernel_launch(void* const* d_in, const int* in_sizes, int n_in,
                              void* d_out, int out_size, void* d_ws, size_t ws_size,
                              hipStream_t stream)
{
  (void)in_sizes; (void)n_in; (void)out_size;
  if (ws_size < (size_t)WS_NEED) return;

  const float* x  = (const float*)d_in[0];
  const float* W0 = (const float*)d_in[1];
  const float* W1 = (const float*)d_in[2];
  const float* W2 = (const float*)d_in[3];
  const float* W3 = (const float*)d_in[4];
  const float* U0 = (const float*)d_in[5];
  const float* U1 = (const float*)d_in[6];
  const float* U2 = (const float*)d_in[7];
  const float* U3 = (const float*)d_in[8];
  const float* b0 = (const float*)d_in[9];
  const float* b1 = (const float*)d_in[10];
  const float* b2 = (const float*)d_in[11];
  const float* b3 = (const float*)d_in[12];
  float* out = (float*)d_out;

  u64* hbuf = (u64*)d_ws;

  const int n4 = WS_NEED / 16;
  zero_ws_kernel<<<dim3((n4 + 255)/256), dim3(256), 0, stream>>>((uint4*)d_ws, n4);
  lstm_persistent<<<dim3(NWG), dim3(NTHR), 0, stream>>>(
      x, W0,W1,W2,W3, U0,U1,U2,U3, b0,b1,b2,b3, out, hbuf);
}